// Round 1
// baseline (830.529 us; speedup 1.0000x reference)
//
#include <hip/hip_runtime.h>
#include <cstdint>
#include <cstddef>
#include <math.h>

// Problem constants (from reference)
#define NN 50000
#define INCH 128
#define HIDC 32
#define NHEAD 8
#define OUTC 40

// ---------------- CSR build ----------------

__global__ void zero_i32(int* p, int n) {
    int i = blockIdx.x * blockDim.x + threadIdx.x;
    if (i < n) p[i] = 0;
}

__global__ void copy_i32(const int* __restrict__ src, int* __restrict__ dst, int n) {
    int i = blockIdx.x * blockDim.x + threadIdx.x;
    if (i < n) dst[i] = src[i];
}

// edges 0..E-1 from edge_index (row0=src, row1=dst); edges E..E+n-1 are self loops
__global__ void count_deg(const int* __restrict__ ei, int E, int n, int* __restrict__ deg) {
    int e = blockIdx.x * blockDim.x + threadIdx.x;
    if (e >= E + n) return;
    int dst = (e < E) ? ei[E + e] : (e - E);
    atomicAdd(&deg[dst], 1);
}

// single-block exclusive scan over n entries -> row_start[0..n]
__global__ void scan_exclusive(const int* __restrict__ deg, int* __restrict__ row_start, int n) {
    __shared__ int wsum[16];
    __shared__ int carry_s;
    const int tid = threadIdx.x;       // 1024 threads
    const int lane = tid & 63, wid = tid >> 6;
    if (tid == 0) carry_s = 0;
    __syncthreads();
    for (int base = 0; base < n; base += 1024) {
        int i = base + tid;
        int v = (i < n) ? deg[i] : 0;
        // inclusive wave scan
        int s = v;
        #pragma unroll
        for (int off = 1; off < 64; off <<= 1) {
            int t = __shfl_up(s, off, 64);
            if (lane >= off) s += t;
        }
        if (lane == 63) wsum[wid] = s;
        __syncthreads();
        if (wid == 0) {
            int ws = (lane < 16) ? wsum[lane] : 0;
            #pragma unroll
            for (int off = 1; off < 16; off <<= 1) {
                int t = __shfl_up(ws, off, 64);
                if (lane >= off) ws += t;
            }
            if (lane < 16) wsum[lane] = ws;   // inclusive wave sums
        }
        __syncthreads();
        int wexcl = (wid == 0) ? 0 : wsum[wid - 1];
        int carry = carry_s;
        if (i < n) row_start[i] = carry + wexcl + s - v;   // exclusive
        __syncthreads();
        if (tid == 1023) carry_s = carry + wsum[15];
        __syncthreads();
    }
    if (threadIdx.x == 0) row_start[n] = carry_s;
}

__global__ void scatter_edges(const int* __restrict__ ei, int E, int n,
                              int* __restrict__ cursor, int* __restrict__ csr_src) {
    int e = blockIdx.x * blockDim.x + threadIdx.x;
    if (e >= E + n) return;
    int src, dst;
    if (e < E) { src = ei[e]; dst = ei[E + e]; } else { src = dst = e - E; }
    int pos = atomicAdd(&cursor[dst], 1);
    csr_src[pos] = src;
}

// ---------------- fp32 tiled GEMM: C[M,N] = A[M,K] @ B[K,N] (+bias) ----------------

template<int BM, int BN, int BK, int TM, int TN>
__global__ void gemm_f32(const float* __restrict__ A, const float* __restrict__ B,
                         const float* __restrict__ bias, float* __restrict__ C,
                         int M, int N, int K) {
    __shared__ float As[BK][BM + 1];
    __shared__ float Bs[BK][BN + 1];
    const int tid = threadIdx.x;
    const int tx = tid % (BN / TN);
    const int ty = tid / (BN / TN);
    const int rowBase = blockIdx.y * BM;
    const int colBase = blockIdx.x * BN;
    float acc[TM][TN] = {};
    for (int k0 = 0; k0 < K; k0 += BK) {
        for (int idx = tid; idx < BM * BK; idx += 256) {
            int r = idx / BK, kk = idx % BK;
            int row = rowBase + r;
            As[kk][r] = (row < M) ? A[(size_t)row * K + k0 + kk] : 0.f;
        }
        for (int idx = tid; idx < BK * BN; idx += 256) {
            int kk = idx / BN, cc = idx % BN;
            Bs[kk][cc] = B[(size_t)(k0 + kk) * N + colBase + cc];
        }
        __syncthreads();
        for (int kk = 0; kk < BK; ++kk) {
            float a[TM], b[TN];
            #pragma unroll
            for (int r = 0; r < TM; ++r) a[r] = As[kk][ty * TM + r];
            #pragma unroll
            for (int c = 0; c < TN; ++c) b[c] = Bs[kk][tx * TN + c];
            #pragma unroll
            for (int r = 0; r < TM; ++r)
                #pragma unroll
                for (int c = 0; c < TN; ++c) acc[r][c] += a[r] * b[c];
        }
        __syncthreads();
    }
    for (int r = 0; r < TM; ++r) {
        int row = rowBase + ty * TM + r;
        if (row >= M) continue;
        for (int c = 0; c < TN; ++c) {
            int col = colBase + tx * TN + c;
            C[(size_t)row * N + col] = acc[r][c] + (bias ? bias[col] : 0.f);
        }
    }
}

// ---------------- layer-1 GATv2 edge pass + online softmax aggregate ----------------
// one block (256 thr) per node; head = tid/32, ch = tid%32
__global__ void gat_agg1(const float* __restrict__ xl, const float* __restrict__ xr,
                         const float* __restrict__ att, const float* __restrict__ b,
                         const int* __restrict__ row_start, const int* __restrict__ csr_src,
                         float* __restrict__ h1) {
    const int i = blockIdx.x;
    const int t = threadIdx.x;        // h*32+c
    const float xr_c = xr[(size_t)i * 256 + t];
    const float attc = att[t];
    const int p0 = row_start[i], p1 = row_start[i + 1];
    float m = -INFINITY, d = 0.f, acc = 0.f;
    for (int p = p0; p < p1; ++p) {
        int j = csr_src[p];
        float v = xl[(size_t)j * 256 + t];
        float e = v + xr_c;
        e = e > 0.f ? e : 0.2f * e;
        float sc = e * attc;
        #pragma unroll
        for (int off = 16; off > 0; off >>= 1) sc += __shfl_xor(sc, off, 32);
        if (sc > m) {
            float scale = __expf(m - sc);   // exp(-inf)=0 on first edge
            d *= scale; acc *= scale; m = sc;
        }
        float w = __expf(sc - m);
        d += w; acc += w * v;
    }
    float o = acc / d + b[t];
    h1[(size_t)i * 256 + t] = o > 0.f ? o : expm1f(o);
}

// ---------------- layer-2 (1 head, 32 ch): 8 nodes per 256-thread block ----------------
__global__ void gat_agg2(const float* __restrict__ xl, const float* __restrict__ xr,
                         const float* __restrict__ att, const float* __restrict__ b,
                         const int* __restrict__ row_start, const int* __restrict__ csr_src,
                         float* __restrict__ h2, int n) {
    const int g = threadIdx.x >> 5;
    const int c = threadIdx.x & 31;
    const int i = blockIdx.x * 8 + g;
    if (i >= n) return;
    const float xr_c = xr[(size_t)i * 32 + c];
    const float attc = att[c];
    const int p0 = row_start[i], p1 = row_start[i + 1];
    float m = -INFINITY, d = 0.f, acc = 0.f;
    for (int p = p0; p < p1; ++p) {
        int j = csr_src[p];
        float v = xl[(size_t)j * 32 + c];
        float e = v + xr_c;
        e = e > 0.f ? e : 0.2f * e;
        float sc = e * attc;
        #pragma unroll
        for (int off = 16; off > 0; off >>= 1) sc += __shfl_xor(sc, off, 32);
        if (sc > m) {
            float scale = __expf(m - sc);
            d *= scale; acc *= scale; m = sc;
        }
        float w = __expf(sc - m);
        d += w; acc += w * v;
    }
    float o = acc / d + b[c];
    h2[(size_t)i * 32 + c] = o > 0.f ? o : expm1f(o);
}

// ---------------- final: out = [h2 | x] @ Wc + bc ----------------
__global__ void final_gemm(const float* __restrict__ h2, const float* __restrict__ x,
                           const float* __restrict__ Wc, const float* __restrict__ bc,
                           float* __restrict__ out, int M) {
    __shared__ float Ws[160 * 40];
    __shared__ float As[64][33];
    const int tid = threadIdx.x;
    for (int idx = tid; idx < 160 * 40; idx += 256) Ws[idx] = Wc[idx];
    const int rowBase = blockIdx.x * 64;
    const int tx = tid % 8;    // cols tx*5 .. tx*5+4
    const int ty = tid / 8;    // rows ty*2, ty*2+1
    float acc[2][5] = {};
    for (int k0 = 0; k0 < 160; k0 += 32) {
        __syncthreads();
        for (int idx = tid; idx < 64 * 32; idx += 256) {
            int r = idx / 32, kk = idx % 32;
            int row = rowBase + r, k = k0 + kk;
            float v = 0.f;
            if (row < M) v = (k < 32) ? h2[(size_t)row * 32 + k] : x[(size_t)row * 128 + (k - 32)];
            As[r][kk] = v;
        }
        __syncthreads();
        for (int kk = 0; kk < 32; ++kk) {
            int k = k0 + kk;
            float a0 = As[ty * 2 + 0][kk];
            float a1 = As[ty * 2 + 1][kk];
            float w[5];
            #pragma unroll
            for (int c = 0; c < 5; ++c) w[c] = Ws[k * 40 + tx * 5 + c];
            #pragma unroll
            for (int c = 0; c < 5; ++c) { acc[0][c] += a0 * w[c]; acc[1][c] += a1 * w[c]; }
        }
    }
    for (int r = 0; r < 2; ++r) {
        int row = rowBase + ty * 2 + r;
        if (row >= M) continue;
        for (int c = 0; c < 5; ++c)
            out[(size_t)row * 40 + tx * 5 + c] = acc[r][c] + bc[tx * 5 + c];
    }
}

// ---------------- launch ----------------

extern "C" void kernel_launch(void* const* d_in, const int* in_sizes, int n_in,
                              void* d_out, int out_size, void* d_ws, size_t ws_size,
                              hipStream_t stream) {
    const float* x    = (const float*)d_in[0];
    const int*   ei   = (const int*)d_in[1];
    const float* W1l  = (const float*)d_in[2];
    const float* W1r  = (const float*)d_in[3];
    const float* att1 = (const float*)d_in[4];
    const float* b1   = (const float*)d_in[5];
    const float* W2l  = (const float*)d_in[6];
    const float* W2r  = (const float*)d_in[7];
    const float* att2 = (const float*)d_in[8];
    const float* b2   = (const float*)d_in[9];
    const float* Wc   = (const float*)d_in[10];
    const float* bc   = (const float*)d_in[11];
    float* out = (float*)d_out;

    const int n  = NN;
    const int E  = in_sizes[1] / 2;
    const int TE = E + n;

    // workspace layout (floats)
    float* ws = (float*)d_ws;
    size_t off = 0;
    float* xl1 = ws + off; off += (size_t)n * 256;
    float* xr1 = ws + off; off += (size_t)n * 256;
    float* h1  = ws + off; off += (size_t)n * 256;
    float* xl2 = ws + off; off += (size_t)n * 32;
    float* xr2 = ws + off; off += (size_t)n * 32;
    float* h2  = ws + off; off += (size_t)n * 32;
    int* ib = (int*)(ws + off);
    int* row_start = ib;                        // n+1
    int* cursor    = ib + (n + 8);              // n+1
    int* deg       = ib + 2 * (n + 8);          // n
    int* csr_src   = ib + 3 * (n + 8);          // TE

    // --- CSR build ---
    zero_i32<<<(n + 255) / 256, 256, 0, stream>>>(deg, n);
    count_deg<<<(TE + 255) / 256, 256, 0, stream>>>(ei, E, n, deg);
    scan_exclusive<<<1, 1024, 0, stream>>>(deg, row_start, n);
    copy_i32<<<(n + 256) / 256, 256, 0, stream>>>(row_start, cursor, n + 1);
    scatter_edges<<<(TE + 255) / 256, 256, 0, stream>>>(ei, E, n, cursor, csr_src);

    // --- layer 1 ---
    {
        dim3 grid(256 / 64, (n + 63) / 64);
        gemm_f32<64, 64, 16, 4, 4><<<grid, 256, 0, stream>>>(x, W1l, nullptr, xl1, n, 256, 128);
        gemm_f32<64, 64, 16, 4, 4><<<grid, 256, 0, stream>>>(x, W1r, nullptr, xr1, n, 256, 128);
    }
    gat_agg1<<<n, 256, 0, stream>>>(xl1, xr1, att1, b1, row_start, csr_src, h1);

    // --- layer 2 ---
    {
        dim3 grid(1, (n + 63) / 64);
        gemm_f32<64, 32, 16, 4, 2><<<grid, 256, 0, stream>>>(h1, W2l, nullptr, xl2, n, 32, 256);
        gemm_f32<64, 32, 16, 4, 2><<<grid, 256, 0, stream>>>(h1, W2r, nullptr, xr2, n, 32, 256);
    }
    gat_agg2<<<(n + 7) / 8, 256, 0, stream>>>(xl2, xr2, att2, b2, row_start, csr_src, h2, n);

    // --- classifier ---
    final_gemm<<<(n + 63) / 64, 256, 0, stream>>>(h2, x, Wc, bc, out, n);
}

// Round 2
// 516.989 us; speedup vs baseline: 1.6065x; 1.6065x over previous
//
#include <hip/hip_runtime.h>
#include <cstdint>
#include <cstddef>
#include <math.h>

#define NN 50000
#define INCH 128
#define HIDC 32
#define NHEAD 8
#define OUTC 40

typedef unsigned short ushort_t;

__device__ __forceinline__ float bf2f(unsigned short h) {
    return __uint_as_float(((unsigned int)h) << 16);
}
__device__ __forceinline__ unsigned short f2bf(float f) {
    unsigned int u = __float_as_uint(f);
    u = u + 0x7FFFu + ((u >> 16) & 1u);   // RNE
    return (unsigned short)(u >> 16);
}

// ---------------- CSR build ----------------

__global__ void zero_i32(int* p, int n) {
    int i = blockIdx.x * blockDim.x + threadIdx.x;
    if (i < n) p[i] = 0;
}

__global__ void copy_i32(const int* __restrict__ src, int* __restrict__ dst, int n) {
    int i = blockIdx.x * blockDim.x + threadIdx.x;
    if (i < n) dst[i] = src[i];
}

__global__ void count_deg(const int* __restrict__ ei, int E, int n, int* __restrict__ deg) {
    int e = blockIdx.x * blockDim.x + threadIdx.x;
    if (e >= E + n) return;
    int dst = (e < E) ? ei[E + e] : (e - E);
    atomicAdd(&deg[dst], 1);
}

__global__ void scan_exclusive(const int* __restrict__ deg, int* __restrict__ row_start, int n) {
    __shared__ int wsum[16];
    __shared__ int carry_s;
    const int tid = threadIdx.x;       // 1024 threads
    const int lane = tid & 63, wid = tid >> 6;
    if (tid == 0) carry_s = 0;
    __syncthreads();
    for (int base = 0; base < n; base += 1024) {
        int i = base + tid;
        int v = (i < n) ? deg[i] : 0;
        int s = v;
        #pragma unroll
        for (int off = 1; off < 64; off <<= 1) {
            int t = __shfl_up(s, off, 64);
            if (lane >= off) s += t;
        }
        if (lane == 63) wsum[wid] = s;
        __syncthreads();
        if (wid == 0) {
            int ws = (lane < 16) ? wsum[lane] : 0;
            #pragma unroll
            for (int off = 1; off < 16; off <<= 1) {
                int t = __shfl_up(ws, off, 64);
                if (lane >= off) ws += t;
            }
            if (lane < 16) wsum[lane] = ws;
        }
        __syncthreads();
        int wexcl = (wid == 0) ? 0 : wsum[wid - 1];
        int carry = carry_s;
        if (i < n) row_start[i] = carry + wexcl + s - v;
        __syncthreads();
        if (tid == 1023) carry_s = carry + wsum[15];
        __syncthreads();
    }
    if (threadIdx.x == 0) row_start[n] = carry_s;
}

__global__ void scatter_edges(const int* __restrict__ ei, int E, int n,
                              int* __restrict__ cursor, int* __restrict__ csr_src) {
    int e = blockIdx.x * blockDim.x + threadIdx.x;
    if (e >= E + n) return;
    int src, dst;
    if (e < E) { src = ei[e]; dst = ei[E + e]; } else { src = dst = e - E; }
    int pos = atomicAdd(&cursor[dst], 1);
    csr_src[pos] = src;
}

// ---------------- layer-1 fused GEMM: [M,128] @ ([128,256]|[128,256]) ----------------
// grid.x = 4 col tiles of 128 (0,1 -> W1l -> xl1 bf16 ; 2,3 -> W1r -> xr1 fp32)
__global__ __launch_bounds__(256) void gemm1_fused(
    const float* __restrict__ A, const float* __restrict__ W1l, const float* __restrict__ W1r,
    ushort_t* __restrict__ xl1, float* __restrict__ xr1, int M) {
    __shared__ float As[16][132];
    __shared__ float Bs[16][132];
    const int tid = threadIdx.x;
    const int bx = blockIdx.x;
    const int rowBase = blockIdx.y * 128;
    const bool isl = bx < 2;
    const float* __restrict__ W = isl ? W1l : W1r;
    const int colW = (bx & 1) * 128;

    const int tx = tid & 15, ty = tid >> 4;
    const int arow = tid >> 2, aseg = tid & 3;     // A stage: row 0..63 (+64), k seg
    const int bkk = tid >> 5, bc4 = tid & 31;      // B stage: kk 0..7 (+8), col4

    float4 aS[2], bS[2];
    {
        #pragma unroll
        for (int h = 0; h < 2; ++h) {
            int row = rowBase + arow + h * 64;
            aS[h] = (row < M) ? *(const float4*)(A + (size_t)row * 128 + aseg * 4)
                              : make_float4(0.f, 0.f, 0.f, 0.f);
            bS[h] = *(const float4*)(W + (size_t)(bkk + h * 8) * 256 + colW + bc4 * 4);
        }
    }
    float acc[2][2][4][4] = {};
    for (int t = 0; t < 8; ++t) {
        #pragma unroll
        for (int h = 0; h < 2; ++h) {
            int r = arow + h * 64;
            As[aseg * 4 + 0][r] = aS[h].x;
            As[aseg * 4 + 1][r] = aS[h].y;
            As[aseg * 4 + 2][r] = aS[h].z;
            As[aseg * 4 + 3][r] = aS[h].w;
            *(float4*)&Bs[bkk + h * 8][bc4 * 4] = bS[h];
        }
        __syncthreads();
        if (t < 7) {
            int k0 = (t + 1) * 16;
            #pragma unroll
            for (int h = 0; h < 2; ++h) {
                int row = rowBase + arow + h * 64;
                aS[h] = (row < M) ? *(const float4*)(A + (size_t)row * 128 + k0 + aseg * 4)
                                  : make_float4(0.f, 0.f, 0.f, 0.f);
                bS[h] = *(const float4*)(W + (size_t)(k0 + bkk + h * 8) * 256 + colW + bc4 * 4);
            }
        }
        #pragma unroll
        for (int kk = 0; kk < 16; ++kk) {
            float4 a0 = *(const float4*)&As[kk][ty * 4];
            float4 a1 = *(const float4*)&As[kk][64 + ty * 4];
            float4 b0 = *(const float4*)&Bs[kk][tx * 4];
            float4 b1 = *(const float4*)&Bs[kk][64 + tx * 4];
            float ar[2][4] = {{a0.x, a0.y, a0.z, a0.w}, {a1.x, a1.y, a1.z, a1.w}};
            float br[2][4] = {{b0.x, b0.y, b0.z, b0.w}, {b1.x, b1.y, b1.z, b1.w}};
            #pragma unroll
            for (int rh = 0; rh < 2; ++rh)
                #pragma unroll
                for (int ch = 0; ch < 2; ++ch)
                    #pragma unroll
                    for (int rr = 0; rr < 4; ++rr)
                        #pragma unroll
                        for (int cc = 0; cc < 4; ++cc)
                            acc[rh][ch][rr][cc] += ar[rh][rr] * br[ch][cc];
        }
        __syncthreads();
    }
    #pragma unroll
    for (int rh = 0; rh < 2; ++rh)
        #pragma unroll
        for (int rr = 0; rr < 4; ++rr) {
            int row = rowBase + rh * 64 + ty * 4 + rr;
            if (row >= M) continue;
            #pragma unroll
            for (int ch = 0; ch < 2; ++ch) {
                int colT = ch * 64 + tx * 4;
                int gcol = bx * 128 + colT;
                if (isl) {
                    ushort4 u;
                    u.x = f2bf(acc[rh][ch][rr][0]);
                    u.y = f2bf(acc[rh][ch][rr][1]);
                    u.z = f2bf(acc[rh][ch][rr][2]);
                    u.w = f2bf(acc[rh][ch][rr][3]);
                    *(ushort4*)(xl1 + (size_t)row * 256 + gcol) = u;
                } else {
                    *(float4*)(xr1 + (size_t)row * 256 + (gcol - 256)) =
                        make_float4(acc[rh][ch][rr][0], acc[rh][ch][rr][1],
                                    acc[rh][ch][rr][2], acc[rh][ch][rr][3]);
                }
            }
        }
}

// ---------------- layer-1 aggregation: one wave per node ----------------
// lane l: head = l>>3, channels (l&7)*4.. within head -> global ch = l*4..l*4+3
__global__ __launch_bounds__(256) void gat_agg1(
    const ushort_t* __restrict__ xl, const float* __restrict__ xr,
    const float* __restrict__ att, const float* __restrict__ b,
    const int* __restrict__ row_start, const int* __restrict__ csr_src,
    float* __restrict__ h1) {
    const int lane = threadIdx.x & 63;
    const int i = blockIdx.x * 4 + (threadIdx.x >> 6);
    const float4 xr4 = *(const float4*)(xr + (size_t)i * 256 + lane * 4);
    const float4 at4 = *(const float4*)(att + lane * 4);
    const int p0 = row_start[i], p1 = row_start[i + 1];
    float m = -INFINITY, d = 0.f;
    float a0 = 0.f, a1 = 0.f, a2 = 0.f, a3 = 0.f;
    ushort4 u = *(const ushort4*)(xl + (size_t)csr_src[p0] * 256 + lane * 4);
    for (int p = p0; p < p1; ++p) {
        float v0 = bf2f(u.x), v1 = bf2f(u.y), v2 = bf2f(u.z), v3 = bf2f(u.w);
        if (p + 1 < p1)
            u = *(const ushort4*)(xl + (size_t)csr_src[p + 1] * 256 + lane * 4);
        float e0 = v0 + xr4.x; e0 = fmaxf(e0, 0.f) + 0.2f * fminf(e0, 0.f);
        float e1 = v1 + xr4.y; e1 = fmaxf(e1, 0.f) + 0.2f * fminf(e1, 0.f);
        float e2 = v2 + xr4.z; e2 = fmaxf(e2, 0.f) + 0.2f * fminf(e2, 0.f);
        float e3 = v3 + xr4.w; e3 = fmaxf(e3, 0.f) + 0.2f * fminf(e3, 0.f);
        float sc = e0 * at4.x;
        sc = fmaf(e1, at4.y, sc);
        sc = fmaf(e2, at4.z, sc);
        sc = fmaf(e3, at4.w, sc);
        sc += __shfl_xor(sc, 1);
        sc += __shfl_xor(sc, 2);
        sc += __shfl_xor(sc, 4);
        float mn = fmaxf(m, sc);
        float corr = __expf(m - mn);      // first iter: exp(-inf)=0
        float w = __expf(sc - mn);
        d = d * corr + w;
        a0 = a0 * corr + w * v0;
        a1 = a1 * corr + w * v1;
        a2 = a2 * corr + w * v2;
        a3 = a3 * corr + w * v3;
        m = mn;
    }
    const float4 bb = *(const float4*)(b + lane * 4);
    float inv = 1.f / d;
    float o0 = a0 * inv + bb.x, o1 = a1 * inv + bb.y;
    float o2 = a2 * inv + bb.z, o3 = a3 * inv + bb.w;
    o0 = o0 > 0.f ? o0 : __expf(o0) - 1.f;
    o1 = o1 > 0.f ? o1 : __expf(o1) - 1.f;
    o2 = o2 > 0.f ? o2 : __expf(o2) - 1.f;
    o3 = o3 > 0.f ? o3 : __expf(o3) - 1.f;
    *(float4*)(h1 + (size_t)i * 256 + lane * 4) = make_float4(o0, o1, o2, o3);
}

// ---------------- layer-2 fused GEMM: [M,256] @ ([256,32]|[256,32]) ----------------
__global__ __launch_bounds__(256) void gemm2_fused(
    const float* __restrict__ A, const float* __restrict__ W2l, const float* __restrict__ W2r,
    ushort_t* __restrict__ xl2, float* __restrict__ xr2, int M) {
    __shared__ float As[32][68];
    __shared__ float Bs[32][68];
    const int tid = threadIdx.x;
    const int rowBase = blockIdx.x * 64;
    const int tx = tid & 15, ty = tid >> 4;

    float4 aS[2], bS[2];
    #pragma unroll
    for (int h = 0; h < 2; ++h) {
        int idx = tid + h * 256;
        int row = rowBase + (idx >> 3);
        int seg = idx & 7;
        aS[h] = (row < M) ? *(const float4*)(A + (size_t)row * 256 + seg * 4)
                          : make_float4(0.f, 0.f, 0.f, 0.f);
        int kk = idx >> 4, c4 = idx & 15;
        int c = c4 * 4;
        bS[h] = (c < 32) ? *(const float4*)(W2l + (size_t)kk * 32 + c)
                         : *(const float4*)(W2r + (size_t)kk * 32 + (c - 32));
    }
    float acc[4][4] = {};
    for (int t = 0; t < 8; ++t) {
        #pragma unroll
        for (int h = 0; h < 2; ++h) {
            int idx = tid + h * 256;
            int r = idx >> 3, seg = idx & 7;
            As[seg * 4 + 0][r] = aS[h].x;
            As[seg * 4 + 1][r] = aS[h].y;
            As[seg * 4 + 2][r] = aS[h].z;
            As[seg * 4 + 3][r] = aS[h].w;
            int kk = idx >> 4, c4 = idx & 15;
            *(float4*)&Bs[kk][c4 * 4] = bS[h];
        }
        __syncthreads();
        if (t < 7) {
            int k0 = (t + 1) * 32;
            #pragma unroll
            for (int h = 0; h < 2; ++h) {
                int idx = tid + h * 256;
                int row = rowBase + (idx >> 3);
                int seg = idx & 7;
                aS[h] = (row < M) ? *(const float4*)(A + (size_t)row * 256 + k0 + seg * 4)
                                  : make_float4(0.f, 0.f, 0.f, 0.f);
                int kk = idx >> 4, c4 = idx & 15;
                int c = c4 * 4;
                bS[h] = (c < 32) ? *(const float4*)(W2l + (size_t)(k0 + kk) * 32 + c)
                                 : *(const float4*)(W2r + (size_t)(k0 + kk) * 32 + (c - 32));
            }
        }
        #pragma unroll
        for (int kk = 0; kk < 32; ++kk) {
            float4 a = *(const float4*)&As[kk][ty * 4];
            float4 bv = *(const float4*)&Bs[kk][tx * 4];
            float ar[4] = {a.x, a.y, a.z, a.w};
            float br[4] = {bv.x, bv.y, bv.z, bv.w};
            #pragma unroll
            for (int rr = 0; rr < 4; ++rr)
                #pragma unroll
                for (int cc = 0; cc < 4; ++cc)
                    acc[rr][cc] += ar[rr] * br[cc];
        }
        __syncthreads();
    }
    #pragma unroll
    for (int rr = 0; rr < 4; ++rr) {
        int row = rowBase + ty * 4 + rr;
        if (row >= M) continue;
        int col = tx * 4;
        if (col < 32) {
            ushort4 u;
            u.x = f2bf(acc[rr][0]); u.y = f2bf(acc[rr][1]);
            u.z = f2bf(acc[rr][2]); u.w = f2bf(acc[rr][3]);
            *(ushort4*)(xl2 + (size_t)row * 32 + col) = u;
        } else {
            *(float4*)(xr2 + (size_t)row * 32 + (col - 32)) =
                make_float4(acc[rr][0], acc[rr][1], acc[rr][2], acc[rr][3]);
        }
    }
}

// ---------------- layer-2 aggregation: 16 lanes per node ----------------
__global__ __launch_bounds__(256) void gat_agg2(
    const ushort_t* __restrict__ xl, const float* __restrict__ xr,
    const float* __restrict__ att, const float* __restrict__ b,
    const int* __restrict__ row_start, const int* __restrict__ csr_src,
    float* __restrict__ h2) {
    const int sub = threadIdx.x & 15;
    const int i = blockIdx.x * 16 + (threadIdx.x >> 4);
    const float2 xrv = *(const float2*)(xr + (size_t)i * 32 + sub * 2);
    const float2 atv = *(const float2*)(att + sub * 2);
    const int p0 = row_start[i], p1 = row_start[i + 1];
    float m = -INFINITY, d = 0.f, a0 = 0.f, a1 = 0.f;
    ushort2 u = *(const ushort2*)(xl + (size_t)csr_src[p0] * 32 + sub * 2);
    for (int p = p0; p < p1; ++p) {
        float v0 = bf2f(u.x), v1 = bf2f(u.y);
        if (p + 1 < p1)
            u = *(const ushort2*)(xl + (size_t)csr_src[p + 1] * 32 + sub * 2);
        float e0 = v0 + xrv.x; e0 = fmaxf(e0, 0.f) + 0.2f * fminf(e0, 0.f);
        float e1 = v1 + xrv.y; e1 = fmaxf(e1, 0.f) + 0.2f * fminf(e1, 0.f);
        float sc = fmaf(e1, atv.y, e0 * atv.x);
        sc += __shfl_xor(sc, 1);
        sc += __shfl_xor(sc, 2);
        sc += __shfl_xor(sc, 4);
        sc += __shfl_xor(sc, 8);
        float mn = fmaxf(m, sc);
        float corr = __expf(m - mn);
        float w = __expf(sc - mn);
        d = d * corr + w;
        a0 = a0 * corr + w * v0;
        a1 = a1 * corr + w * v1;
        m = mn;
    }
    float inv = 1.f / d;
    float o0 = a0 * inv + b[sub * 2];
    float o1 = a1 * inv + b[sub * 2 + 1];
    o0 = o0 > 0.f ? o0 : __expf(o0) - 1.f;
    o1 = o1 > 0.f ? o1 : __expf(o1) - 1.f;
    *(float2*)(h2 + (size_t)i * 32 + sub * 2) = make_float2(o0, o1);
}

// ---------------- final: out = [h2 | x] @ Wc + bc ----------------
__global__ __launch_bounds__(256) void final_gemm(
    const float* __restrict__ h2, const float* __restrict__ x,
    const float* __restrict__ Wc, const float* __restrict__ bc,
    float* __restrict__ out, int M) {
    __shared__ float Ws[160 * 40];
    __shared__ float As[32][68];
    const int tid = threadIdx.x;
    const int rowBase = blockIdx.x * 64;
    const int tx = tid & 7, ty = tid >> 3;   // cols tx*5.., rows ty*2..
    for (int idx = tid; idx < 160 * 40; idx += 256) Ws[idx] = Wc[idx];
    float acc[2][5] = {};
    for (int t = 0; t < 5; ++t) {
        __syncthreads();
        #pragma unroll
        for (int h = 0; h < 2; ++h) {
            int idx = tid + h * 256;
            int r = idx >> 3, seg = idx & 7;
            int row = rowBase + r;
            float4 v = make_float4(0.f, 0.f, 0.f, 0.f);
            if (row < M) {
                if (t == 0) v = *(const float4*)(h2 + (size_t)row * 32 + seg * 4);
                else        v = *(const float4*)(x + (size_t)row * 128 + (t - 1) * 32 + seg * 4);
            }
            As[seg * 4 + 0][r] = v.x;
            As[seg * 4 + 1][r] = v.y;
            As[seg * 4 + 2][r] = v.z;
            As[seg * 4 + 3][r] = v.w;
        }
        __syncthreads();
        for (int kk = 0; kk < 32; ++kk) {
            int k = t * 32 + kk;
            float a0 = As[kk][ty * 2 + 0];
            float a1 = As[kk][ty * 2 + 1];
            float w[5];
            #pragma unroll
            for (int c = 0; c < 5; ++c) w[c] = Ws[k * 40 + tx * 5 + c];
            #pragma unroll
            for (int c = 0; c < 5; ++c) {
                acc[0][c] = fmaf(a0, w[c], acc[0][c]);
                acc[1][c] = fmaf(a1, w[c], acc[1][c]);
            }
        }
    }
    #pragma unroll
    for (int r = 0; r < 2; ++r) {
        int row = rowBase + ty * 2 + r;
        if (row >= M) continue;
        #pragma unroll
        for (int c = 0; c < 5; ++c)
            out[(size_t)row * 40 + tx * 5 + c] = acc[r][c] + bc[tx * 5 + c];
    }
}

// ---------------- launch ----------------

extern "C" void kernel_launch(void* const* d_in, const int* in_sizes, int n_in,
                              void* d_out, int out_size, void* d_ws, size_t ws_size,
                              hipStream_t stream) {
    const float* x    = (const float*)d_in[0];
    const int*   ei   = (const int*)d_in[1];
    const float* W1l  = (const float*)d_in[2];
    const float* W1r  = (const float*)d_in[3];
    const float* att1 = (const float*)d_in[4];
    const float* b1   = (const float*)d_in[5];
    const float* W2l  = (const float*)d_in[6];
    const float* W2r  = (const float*)d_in[7];
    const float* att2 = (const float*)d_in[8];
    const float* b2   = (const float*)d_in[9];
    const float* Wc   = (const float*)d_in[10];
    const float* bc   = (const float*)d_in[11];
    float* out = (float*)d_out;

    const int n  = NN;
    const int E  = in_sizes[1] / 2;
    const int TE = E + n;

    // workspace layout (byte offsets, 256B aligned)
    char* ws = (char*)d_ws;
    size_t off = 0;
    auto alloc = [&](size_t bytes) { void* p = ws + off; off += (bytes + 255) & ~(size_t)255; return p; };
    ushort_t* xl1 = (ushort_t*)alloc((size_t)n * 256 * 2);
    float*    xr1 = (float*)alloc((size_t)n * 256 * 4);
    float*    h1  = (float*)alloc((size_t)n * 256 * 4);
    ushort_t* xl2 = (ushort_t*)alloc((size_t)n * 32 * 2);
    float*    xr2 = (float*)alloc((size_t)n * 32 * 4);
    float*    h2  = (float*)alloc((size_t)n * 32 * 4);
    int* row_start = (int*)alloc((size_t)(n + 1) * 4);
    int* cursor    = (int*)alloc((size_t)(n + 1) * 4);
    int* deg       = (int*)alloc((size_t)n * 4);
    int* csr_src   = (int*)alloc((size_t)TE * 4);

    // --- CSR build ---
    zero_i32<<<(n + 255) / 256, 256, 0, stream>>>(deg, n);
    count_deg<<<(TE + 255) / 256, 256, 0, stream>>>(ei, E, n, deg);
    scan_exclusive<<<1, 1024, 0, stream>>>(deg, row_start, n);
    copy_i32<<<(n + 256) / 256, 256, 0, stream>>>(row_start, cursor, n + 1);
    scatter_edges<<<(TE + 255) / 256, 256, 0, stream>>>(ei, E, n, cursor, csr_src);

    // --- layer 1 ---
    gemm1_fused<<<dim3(4, (n + 127) / 128), 256, 0, stream>>>(x, W1l, W1r, xl1, xr1, n);
    gat_agg1<<<n / 4, 256, 0, stream>>>(xl1, xr1, att1, b1, row_start, csr_src, h1);

    // --- layer 2 ---
    gemm2_fused<<<(n + 63) / 64, 256, 0, stream>>>(h1, W2l, W2r, xl2, xr2, n);
    gat_agg2<<<n / 16, 256, 0, stream>>>(xl2, xr2, att2, b2, row_start, csr_src, h2);

    // --- classifier ---
    final_gemm<<<(n + 63) / 64, 256, 0, stream>>>(h2, x, Wc, bc, out, n);
}

// Round 3
// 368.614 us; speedup vs baseline: 2.2531x; 1.4025x over previous
//
#include <hip/hip_runtime.h>
#include <cstdint>
#include <cstddef>
#include <math.h>

#define NN 50000
#define INCH 128
#define HIDC 32
#define NHEAD 8
#define OUTC 40

typedef unsigned short ushort_t;
using bf16x8 = __attribute__((ext_vector_type(8))) short;
using f32x4  = __attribute__((ext_vector_type(4))) float;

__device__ __forceinline__ float bf2f(unsigned short h) {
    return __uint_as_float(((unsigned int)h) << 16);
}
__device__ __forceinline__ unsigned short f2bf(float f) {
    unsigned int u = __float_as_uint(f);
    u = u + 0x7FFFu + ((u >> 16) & 1u);   // RNE
    return (unsigned short)(u >> 16);
}

// ---------------- input conversion ----------------

// x [n*128] fp32 -> xb bf16 ; 8 floats per thread
__global__ __launch_bounds__(256) void convert_x(const float* __restrict__ x,
                                                 ushort_t* __restrict__ xb, int total8) {
    int i = blockIdx.x * 256 + threadIdx.x;
    if (i >= total8) return;
    float4 f0 = *(const float4*)(x + (size_t)i * 8);
    float4 f1 = *(const float4*)(x + (size_t)i * 8 + 4);
    ushort4 u0, u1;
    u0.x = f2bf(f0.x); u0.y = f2bf(f0.y); u0.z = f2bf(f0.z); u0.w = f2bf(f0.w);
    u1.x = f2bf(f1.x); u1.y = f2bf(f1.y); u1.z = f2bf(f1.z); u1.w = f2bf(f1.w);
    *(ushort4*)(xb + (size_t)i * 8) = u0;
    *(ushort4*)(xb + (size_t)i * 8 + 4) = u1;
}

// weights -> transposed bf16: BT1[512][128], BT2[64][256], BTc[40][160]
__global__ __launch_bounds__(256) void prep_weights(
    const float* __restrict__ W1l, const float* __restrict__ W1r,
    const float* __restrict__ W2l, const float* __restrict__ W2r,
    const float* __restrict__ Wc,
    ushort_t* __restrict__ BT1, ushort_t* __restrict__ BT2, ushort_t* __restrict__ BTc) {
    int b = blockIdx.x, k = threadIdx.x;
    if (b < 512) {             // BT1: c = b, k < 128
        if (k < 128) {
            float v = (b < 256) ? W1l[(size_t)k * 256 + b] : W1r[(size_t)k * 256 + (b - 256)];
            BT1[(size_t)b * 128 + k] = f2bf(v);
        }
    } else if (b < 576) {      // BT2: c = b-512, k < 256
        int c = b - 512;
        float v = (c < 32) ? W2l[(size_t)k * 32 + c] : W2r[(size_t)k * 32 + (c - 32)];
        BT2[(size_t)c * 256 + k] = f2bf(v);
    } else {                   // BTc: c = b-576, k < 160
        int c = b - 576;
        if (k < 160) BTc[(size_t)c * 160 + k] = f2bf(Wc[(size_t)k * 40 + c]);
    }
}

// ---------------- CSR build ----------------

__global__ void zero_i32(int* p, int n) {
    int i = blockIdx.x * blockDim.x + threadIdx.x;
    if (i < n) p[i] = 0;
}

__global__ void count_deg(const int* __restrict__ ei, int E, int n, int* __restrict__ deg) {
    int e = blockIdx.x * blockDim.x + threadIdx.x;
    if (e >= E + n) return;
    int dst = (e < E) ? ei[E + e] : (e - E);
    atomicAdd(&deg[dst], 1);
}

// block-local exclusive scan over 1024-chunks
__global__ __launch_bounds__(1024) void partial_scan(
    const int* __restrict__ deg, int* __restrict__ row_start,
    int* __restrict__ block_total, int n) {
    __shared__ int wsum[16];
    const int tid = threadIdx.x, lane = tid & 63, wid = tid >> 6;
    int i = blockIdx.x * 1024 + tid;
    int v = (i < n) ? deg[i] : 0;
    int s = v;
    #pragma unroll
    for (int off = 1; off < 64; off <<= 1) {
        int t = __shfl_up(s, off, 64);
        if (lane >= off) s += t;
    }
    if (lane == 63) wsum[wid] = s;
    __syncthreads();
    if (wid == 0) {
        int ws = (lane < 16) ? wsum[lane] : 0;
        #pragma unroll
        for (int off = 1; off < 16; off <<= 1) {
            int t = __shfl_up(ws, off, 64);
            if (lane >= off) ws += t;
        }
        if (lane < 16) wsum[lane] = ws;
    }
    __syncthreads();
    int wexcl = wid ? wsum[wid - 1] : 0;
    if (i < n) row_start[i] = wexcl + s - v;
    if (tid == 0) block_total[blockIdx.x] = wsum[15];
}

__global__ void totals_scan(const int* __restrict__ block_total, int* __restrict__ block_off,
                            int* __restrict__ row_start_n, int nb) {
    int j = threadIdx.x;    // 64 threads
    int v = (j < nb) ? block_total[j] : 0;
    int s = v;
    #pragma unroll
    for (int off = 1; off < 64; off <<= 1) {
        int t = __shfl_up(s, off, 64);
        if (j >= off) s += t;
    }
    if (j < nb) block_off[j] = s - v;
    if (j == nb - 1) *row_start_n = s;
}

__global__ __launch_bounds__(1024) void add_off(int* __restrict__ row_start, int* __restrict__ cursor,
                                                const int* __restrict__ block_off, int n) {
    int i = blockIdx.x * 1024 + threadIdx.x;
    if (i >= n) return;
    int val = row_start[i] + block_off[blockIdx.x];
    row_start[i] = val;
    cursor[i] = val;
}

__global__ void scatter_edges(const int* __restrict__ ei, int E, int n,
                              int* __restrict__ cursor, int* __restrict__ csr_src) {
    int e = blockIdx.x * blockDim.x + threadIdx.x;
    if (e >= E + n) return;
    int src, dst;
    if (e < E) { src = ei[e]; dst = ei[E + e]; } else { src = dst = e - E; }
    int pos = atomicAdd(&cursor[dst], 1);
    csr_src[pos] = src;
}

// ---------------- MFMA GEMM 1: xlr1[M,512] = xb[M,128] @ BT1^T ----------------
// grid (4 col-tiles, ceil(M/128)); 256 thr = 4 waves 2x2, each 64x64
__global__ __launch_bounds__(256) void gemm1_mfma(
    const ushort_t* __restrict__ xb, const ushort_t* __restrict__ BT1,
    ushort_t* __restrict__ xlr1, int M) {
    __shared__ ushort_t As[128][72];
    __shared__ ushort_t Bs[128][72];
    const int tid = threadIdx.x;
    const int rowBase = blockIdx.y * 128;
    const int c0 = blockIdx.x * 128;
    const int wid = tid >> 6, lane = tid & 63;
    const int wr = wid >> 1, wc = wid & 1;
    const int l15 = lane & 15, l4 = lane >> 4;
    f32x4 acc[4][4];
    #pragma unroll
    for (int i = 0; i < 4; ++i)
        #pragma unroll
        for (int j = 0; j < 4; ++j)
            #pragma unroll
            for (int q = 0; q < 4; ++q) acc[i][j][q] = 0.f;

    for (int c = 0; c < 2; ++c) {     // K chunks of 64
        #pragma unroll
        for (int h = 0; h < 4; ++h) {
            int idx = h * 256 + tid;          // 0..1023
            int r = idx >> 3, seg = idx & 7;  // seg*8 = k within chunk
            int row = rowBase + r;
            uint4 v = {0, 0, 0, 0};
            if (row < M) v = *(const uint4*)(xb + (size_t)row * 128 + c * 64 + seg * 8);
            *(uint4*)&As[r][seg * 8] = v;
            *(uint4*)&Bs[r][seg * 8] = *(const uint4*)(BT1 + (size_t)(c0 + r) * 128 + c * 64 + seg * 8);
        }
        __syncthreads();
        #pragma unroll
        for (int kk = 0; kk < 2; ++kk) {
            bf16x8 a[4], b[4];
            #pragma unroll
            for (int f = 0; f < 4; ++f) {
                a[f] = *(const bf16x8*)&As[wr * 64 + f * 16 + l15][kk * 32 + l4 * 8];
                b[f] = *(const bf16x8*)&Bs[wc * 64 + f * 16 + l15][kk * 32 + l4 * 8];
            }
            #pragma unroll
            for (int i = 0; i < 4; ++i)
                #pragma unroll
                for (int j = 0; j < 4; ++j)
                    acc[i][j] = __builtin_amdgcn_mfma_f32_16x16x32_bf16(a[i], b[j], acc[i][j], 0, 0, 0);
        }
        __syncthreads();
    }
    #pragma unroll
    for (int i = 0; i < 4; ++i)
        #pragma unroll
        for (int r = 0; r < 4; ++r) {
            int row = rowBase + wr * 64 + i * 16 + l4 * 4 + r;
            if (row >= M) continue;
            #pragma unroll
            for (int j = 0; j < 4; ++j) {
                int col = c0 + wc * 64 + j * 16 + l15;
                xlr1[(size_t)row * 512 + col] = f2bf(acc[i][j][r]);
            }
        }
}

// ---------------- MFMA GEMM 2: xlr2[M,64] = h1[M,256] @ BT2^T ----------------
// 4 waves row-split, each 32x64
__global__ __launch_bounds__(256) void gemm2_mfma(
    const ushort_t* __restrict__ h1, const ushort_t* __restrict__ BT2,
    ushort_t* __restrict__ xlr2, int M) {
    __shared__ ushort_t As[128][72];
    __shared__ ushort_t Bs[64][264];
    const int tid = threadIdx.x;
    const int rowBase = blockIdx.x * 128;
    const int wid = tid >> 6, lane = tid & 63;
    const int l15 = lane & 15, l4 = lane >> 4;
    // stage B fully
    #pragma unroll
    for (int h = 0; h < 8; ++h) {
        int idx = h * 256 + tid;            // 0..2047
        int r = idx >> 5, seg = idx & 31;
        *(uint4*)&Bs[r][seg * 8] = *(const uint4*)(BT2 + (size_t)r * 256 + seg * 8);
    }
    f32x4 acc[2][4];
    #pragma unroll
    for (int i = 0; i < 2; ++i)
        #pragma unroll
        for (int j = 0; j < 4; ++j)
            #pragma unroll
            for (int q = 0; q < 4; ++q) acc[i][j][q] = 0.f;

    for (int c = 0; c < 4; ++c) {       // K chunks of 64
        #pragma unroll
        for (int h = 0; h < 4; ++h) {
            int idx = h * 256 + tid;
            int r = idx >> 3, seg = idx & 7;
            int row = rowBase + r;
            uint4 v = {0, 0, 0, 0};
            if (row < M) v = *(const uint4*)(h1 + (size_t)row * 256 + c * 64 + seg * 8);
            *(uint4*)&As[r][seg * 8] = v;
        }
        __syncthreads();
        #pragma unroll
        for (int kk = 0; kk < 2; ++kk) {
            bf16x8 a[2], b[4];
            #pragma unroll
            for (int f = 0; f < 2; ++f)
                a[f] = *(const bf16x8*)&As[wid * 32 + f * 16 + l15][kk * 32 + l4 * 8];
            #pragma unroll
            for (int f = 0; f < 4; ++f)
                b[f] = *(const bf16x8*)&Bs[f * 16 + l15][c * 64 + kk * 32 + l4 * 8];
            #pragma unroll
            for (int i = 0; i < 2; ++i)
                #pragma unroll
                for (int j = 0; j < 4; ++j)
                    acc[i][j] = __builtin_amdgcn_mfma_f32_16x16x32_bf16(a[i], b[j], acc[i][j], 0, 0, 0);
        }
        __syncthreads();
    }
    #pragma unroll
    for (int i = 0; i < 2; ++i)
        #pragma unroll
        for (int r = 0; r < 4; ++r) {
            int row = rowBase + wid * 32 + i * 16 + l4 * 4 + r;
            if (row >= M) continue;
            #pragma unroll
            for (int j = 0; j < 4; ++j) {
                int col = j * 16 + l15;
                xlr2[(size_t)row * 64 + col] = f2bf(acc[i][j][r]);
            }
        }
}

// ---------------- MFMA final: out[M,40] = [h2|xb][M,160] @ BTc^T + bc ----------------
__global__ __launch_bounds__(256) void final_mfma(
    const ushort_t* __restrict__ h2, const ushort_t* __restrict__ xb,
    const ushort_t* __restrict__ BTc, const float* __restrict__ bc,
    float* __restrict__ out, int M) {
    __shared__ ushort_t As[128][168];
    __shared__ ushort_t Bs[48][168];
    const int tid = threadIdx.x;
    const int rowBase = blockIdx.x * 128;
    const int wid = tid >> 6, lane = tid & 63;
    const int l15 = lane & 15, l4 = lane >> 4;
    // stage B (rows 40..47 zero)
    #pragma unroll
    for (int h = 0; h < 4; ++h) {
        int idx = h * 256 + tid;    // < 960
        if (idx < 960) {
            int r = idx / 20, seg = idx % 20;
            uint4 v = {0, 0, 0, 0};
            if (r < 40) v = *(const uint4*)(BTc + (size_t)r * 160 + seg * 8);
            *(uint4*)&Bs[r][seg * 8] = v;
        }
    }
    // stage A: cols 0..31 from h2, 32..159 from xb
    #pragma unroll
    for (int h = 0; h < 10; ++h) {
        int idx = h * 256 + tid;    // < 2560
        int r = idx / 20, seg = idx % 20;
        int row = rowBase + r;
        uint4 v = {0, 0, 0, 0};
        if (row < M)
            v = (seg < 4) ? *(const uint4*)(h2 + (size_t)row * 32 + seg * 8)
                          : *(const uint4*)(xb + (size_t)row * 128 + (seg - 4) * 8);
        *(uint4*)&As[r][seg * 8] = v;
    }
    __syncthreads();
    f32x4 acc[2][3];
    #pragma unroll
    for (int i = 0; i < 2; ++i)
        #pragma unroll
        for (int j = 0; j < 3; ++j)
            #pragma unroll
            for (int q = 0; q < 4; ++q) acc[i][j][q] = 0.f;
    #pragma unroll
    for (int kk = 0; kk < 5; ++kk) {
        bf16x8 a[2], b[3];
        #pragma unroll
        for (int f = 0; f < 2; ++f)
            a[f] = *(const bf16x8*)&As[wid * 32 + f * 16 + l15][kk * 32 + l4 * 8];
        #pragma unroll
        for (int f = 0; f < 3; ++f)
            b[f] = *(const bf16x8*)&Bs[f * 16 + l15][kk * 32 + l4 * 8];
        #pragma unroll
        for (int i = 0; i < 2; ++i)
            #pragma unroll
            for (int j = 0; j < 3; ++j)
                acc[i][j] = __builtin_amdgcn_mfma_f32_16x16x32_bf16(a[i], b[j], acc[i][j], 0, 0, 0);
    }
    #pragma unroll
    for (int i = 0; i < 2; ++i)
        #pragma unroll
        for (int r = 0; r < 4; ++r) {
            int row = rowBase + wid * 32 + i * 16 + l4 * 4 + r;
            if (row >= M) continue;
            #pragma unroll
            for (int j = 0; j < 3; ++j) {
                int col = j * 16 + l15;
                if (col < 40) out[(size_t)row * 40 + col] = acc[i][j][r] + bc[col];
            }
        }
}

// ---------------- layer-1 aggregation: one wave per node ----------------
__global__ __launch_bounds__(256) void gat_agg1(
    const ushort_t* __restrict__ xlr, const float* __restrict__ att, const float* __restrict__ b,
    const int* __restrict__ row_start, const int* __restrict__ csr_src,
    ushort_t* __restrict__ h1) {
    const int lane = threadIdx.x & 63;
    const int i = blockIdx.x * 4 + (threadIdx.x >> 6);
    const ushort4 xru = *(const ushort4*)(xlr + (size_t)i * 512 + 256 + lane * 4);
    const float xr0 = bf2f(xru.x), xr1 = bf2f(xru.y), xr2 = bf2f(xru.z), xr3 = bf2f(xru.w);
    const float4 at4 = *(const float4*)(att + lane * 4);
    const int p0 = row_start[i], p1 = row_start[i + 1];
    float m = -INFINITY, d = 0.f;
    float a0 = 0.f, a1 = 0.f, a2 = 0.f, a3 = 0.f;
    ushort4 u = *(const ushort4*)(xlr + (size_t)csr_src[p0] * 512 + lane * 4);
    for (int p = p0; p < p1; ++p) {
        float v0 = bf2f(u.x), v1 = bf2f(u.y), v2 = bf2f(u.z), v3 = bf2f(u.w);
        if (p + 1 < p1)
            u = *(const ushort4*)(xlr + (size_t)csr_src[p + 1] * 512 + lane * 4);
        float e0 = v0 + xr0; e0 = fmaxf(e0, 0.f) + 0.2f * fminf(e0, 0.f);
        float e1 = v1 + xr1; e1 = fmaxf(e1, 0.f) + 0.2f * fminf(e1, 0.f);
        float e2 = v2 + xr2; e2 = fmaxf(e2, 0.f) + 0.2f * fminf(e2, 0.f);
        float e3 = v3 + xr3; e3 = fmaxf(e3, 0.f) + 0.2f * fminf(e3, 0.f);
        float sc = e0 * at4.x;
        sc = fmaf(e1, at4.y, sc);
        sc = fmaf(e2, at4.z, sc);
        sc = fmaf(e3, at4.w, sc);
        sc += __shfl_xor(sc, 1);
        sc += __shfl_xor(sc, 2);
        sc += __shfl_xor(sc, 4);
        float mn = fmaxf(m, sc);
        float corr = __expf(m - mn);
        float w = __expf(sc - mn);
        d = d * corr + w;
        a0 = a0 * corr + w * v0;
        a1 = a1 * corr + w * v1;
        a2 = a2 * corr + w * v2;
        a3 = a3 * corr + w * v3;
        m = mn;
    }
    const float4 bb = *(const float4*)(b + lane * 4);
    float inv = 1.f / d;
    float o0 = a0 * inv + bb.x, o1 = a1 * inv + bb.y;
    float o2 = a2 * inv + bb.z, o3 = a3 * inv + bb.w;
    o0 = o0 > 0.f ? o0 : __expf(o0) - 1.f;
    o1 = o1 > 0.f ? o1 : __expf(o1) - 1.f;
    o2 = o2 > 0.f ? o2 : __expf(o2) - 1.f;
    o3 = o3 > 0.f ? o3 : __expf(o3) - 1.f;
    ushort4 ou;
    ou.x = f2bf(o0); ou.y = f2bf(o1); ou.z = f2bf(o2); ou.w = f2bf(o3);
    *(ushort4*)(h1 + (size_t)i * 256 + lane * 4) = ou;
}

// ---------------- layer-2 aggregation: 16 lanes per node ----------------
__global__ __launch_bounds__(256) void gat_agg2(
    const ushort_t* __restrict__ xlr, const float* __restrict__ att, const float* __restrict__ b,
    const int* __restrict__ row_start, const int* __restrict__ csr_src,
    ushort_t* __restrict__ h2) {
    const int sub = threadIdx.x & 15;
    const int i = blockIdx.x * 16 + (threadIdx.x >> 4);
    const ushort2 xru = *(const ushort2*)(xlr + (size_t)i * 64 + 32 + sub * 2);
    const float xr0 = bf2f(xru.x), xr1 = bf2f(xru.y);
    const float2 atv = *(const float2*)(att + sub * 2);
    const int p0 = row_start[i], p1 = row_start[i + 1];
    float m = -INFINITY, d = 0.f, a0 = 0.f, a1 = 0.f;
    ushort2 u = *(const ushort2*)(xlr + (size_t)csr_src[p0] * 64 + sub * 2);
    for (int p = p0; p < p1; ++p) {
        float v0 = bf2f(u.x), v1 = bf2f(u.y);
        if (p + 1 < p1)
            u = *(const ushort2*)(xlr + (size_t)csr_src[p + 1] * 64 + sub * 2);
        float e0 = v0 + xr0; e0 = fmaxf(e0, 0.f) + 0.2f * fminf(e0, 0.f);
        float e1 = v1 + xr1; e1 = fmaxf(e1, 0.f) + 0.2f * fminf(e1, 0.f);
        float sc = fmaf(e1, atv.y, e0 * atv.x);
        sc += __shfl_xor(sc, 1);
        sc += __shfl_xor(sc, 2);
        sc += __shfl_xor(sc, 4);
        sc += __shfl_xor(sc, 8);
        float mn = fmaxf(m, sc);
        float corr = __expf(m - mn);
        float w = __expf(sc - mn);
        d = d * corr + w;
        a0 = a0 * corr + w * v0;
        a1 = a1 * corr + w * v1;
        m = mn;
    }
    float inv = 1.f / d;
    float o0 = a0 * inv + b[sub * 2];
    float o1 = a1 * inv + b[sub * 2 + 1];
    o0 = o0 > 0.f ? o0 : __expf(o0) - 1.f;
    o1 = o1 > 0.f ? o1 : __expf(o1) - 1.f;
    ushort2 ou; ou.x = f2bf(o0); ou.y = f2bf(o1);
    *(ushort2*)(h2 + (size_t)i * 32 + sub * 2) = ou;
}

// ---------------- launch ----------------

extern "C" void kernel_launch(void* const* d_in, const int* in_sizes, int n_in,
                              void* d_out, int out_size, void* d_ws, size_t ws_size,
                              hipStream_t stream) {
    const float* x    = (const float*)d_in[0];
    const int*   ei   = (const int*)d_in[1];
    const float* W1l  = (const float*)d_in[2];
    const float* W1r  = (const float*)d_in[3];
    const float* att1 = (const float*)d_in[4];
    const float* b1   = (const float*)d_in[5];
    const float* W2l  = (const float*)d_in[6];
    const float* W2r  = (const float*)d_in[7];
    const float* att2 = (const float*)d_in[8];
    const float* b2   = (const float*)d_in[9];
    const float* Wc   = (const float*)d_in[10];
    const float* bc   = (const float*)d_in[11];
    float* out = (float*)d_out;

    const int n  = NN;
    const int E  = in_sizes[1] / 2;
    const int TE = E + n;
    const int NB = (n + 1023) / 1024;    // scan blocks (49)

    char* ws = (char*)d_ws;
    size_t off = 0;
    auto alloc = [&](size_t bytes) { void* p = ws + off; off += (bytes + 255) & ~(size_t)255; return p; };
    ushort_t* xb   = (ushort_t*)alloc((size_t)n * 128 * 2);
    ushort_t* xlr1 = (ushort_t*)alloc((size_t)n * 512 * 2);
    ushort_t* h1   = (ushort_t*)alloc((size_t)n * 256 * 2);
    ushort_t* xlr2 = (ushort_t*)alloc((size_t)n * 64 * 2);
    ushort_t* h2   = (ushort_t*)alloc((size_t)n * 32 * 2);
    ushort_t* BT1  = (ushort_t*)alloc(512 * 128 * 2);
    ushort_t* BT2  = (ushort_t*)alloc(64 * 256 * 2);
    ushort_t* BTc  = (ushort_t*)alloc(40 * 160 * 2);
    int* row_start   = (int*)alloc((size_t)(n + 1) * 4);
    int* cursor      = (int*)alloc((size_t)(n + 1) * 4);
    int* deg         = (int*)alloc((size_t)n * 4);
    int* block_total = (int*)alloc((size_t)NB * 4);
    int* block_off   = (int*)alloc((size_t)NB * 4);
    int* csr_src     = (int*)alloc((size_t)TE * 4);

    // input prep
    convert_x<<<(n * 128 / 8 + 255) / 256, 256, 0, stream>>>(x, xb, n * 128 / 8);
    prep_weights<<<616, 256, 0, stream>>>(W1l, W1r, W2l, W2r, Wc, BT1, BT2, BTc);

    // CSR build
    zero_i32<<<(n + 255) / 256, 256, 0, stream>>>(deg, n);
    count_deg<<<(TE + 255) / 256, 256, 0, stream>>>(ei, E, n, deg);
    partial_scan<<<NB, 1024, 0, stream>>>(deg, row_start, block_total, n);
    totals_scan<<<1, 64, 0, stream>>>(block_total, block_off, row_start + n, NB);
    add_off<<<NB, 1024, 0, stream>>>(row_start, cursor, block_off, n);
    scatter_edges<<<(TE + 255) / 256, 256, 0, stream>>>(ei, E, n, cursor, csr_src);

    // layer 1
    gemm1_mfma<<<dim3(4, (n + 127) / 128), 256, 0, stream>>>(xb, BT1, xlr1, n);
    gat_agg1<<<n / 4, 256, 0, stream>>>(xlr1, att1, b1, row_start, csr_src, h1);

    // layer 2
    gemm2_mfma<<<(n + 127) / 128, 256, 0, stream>>>(h1, BT2, xlr2, n);
    gat_agg2<<<n / 16, 256, 0, stream>>>(xlr2, att2, b2, row_start, csr_src, h2);

    // classifier
    final_mfma<<<(n + 127) / 128, 256, 0, stream>>>(h2, xb, BTc, bc, out, n);
}